// Round 8
// baseline (254.196 us; speedup 1.0000x reference)
//
#include <hip/hip_runtime.h>

// Problem constants
#define BB 4
#define SS 2048
#define DD 512
#define HH 8
#define DKK 64
#define HDK 512   // H*DK

typedef __attribute__((ext_vector_type(4))) float f32x4;
typedef __attribute__((ext_vector_type(8))) __bf16 bf16x8;
typedef __attribute__((ext_vector_type(4))) __bf16 bf16x4;

#define MFMA16(a, b, c) __builtin_amdgcn_mfma_f32_16x16x32_bf16((a), (b), (c), 0, 0, 0)

#define GLOAD_LDS16(gptr, lptr)                                                    \
    __builtin_amdgcn_global_load_lds(                                              \
        (const __attribute__((address_space(1))) void*)(gptr),                     \
        (__attribute__((address_space(3))) void*)(lptr), 16, 0, 0)

#define WAITCNT_VM(N) do { asm volatile("s_waitcnt vmcnt(" #N ")" ::: "memory");   \
                           __builtin_amdgcn_sched_barrier(0); } while (0)
#define WAITCNT_LGKM0() do { asm volatile("s_waitcnt lgkmcnt(0)" ::: "memory");    \
                             __builtin_amdgcn_sched_barrier(0); } while (0)

__device__ inline bf16x8 cvt48(const f32x4 f0, const f32x4 f1) {
    bf16x8 w;
    w[0] = (__bf16)f0[0]; w[1] = (__bf16)f0[1]; w[2] = (__bf16)f0[2]; w[3] = (__bf16)f0[3];
    w[4] = (__bf16)f1[0]; w[5] = (__bf16)f1[1]; w[6] = (__bf16)f1[2]; w[7] = (__bf16)f1[3];
    return w;
}

// ---------------------------------------------------------------------------
// Kernel 1: projection GEMM, 128x128 tile, BK=32, depth-2 gload_lds pipeline
// with COUNTED vmcnt (T3/T4): per-wave 8 DMAs/tile; steady-state 16 in
// flight, wait vmcnt(8) -> only the older tile drains; raw s_barrier after
// each wave verified its own DMAs => tile globally visible.
//   z=0 -> qh [B,H,S,DK], z=1 -> kh [B,H,S,DK], z=2 -> vt [B,H,DK,S]
// ---------------------------------------------------------------------------
__global__ __launch_bounds__(256) void proj_kernel(
    const float* __restrict__ q, const float* __restrict__ k, const float* __restrict__ v,
    const float* __restrict__ Wq, const float* __restrict__ bq,
    __bf16* __restrict__ qh, __bf16* __restrict__ kh, __bf16* __restrict__ vt)
{
    const int z  = blockIdx.z;
    const float* X = (z == 0) ? q : (z == 1) ? k : v;
    const int m0 = blockIdx.x * 128;
    const int n0 = blockIdx.y * 128;

    __shared__ __align__(16) float As0[128 * 32], Bs0[128 * 32];  // 16 KB each
    __shared__ __align__(16) float As1[128 * 32], Bs1[128 * 32];

    const int t    = threadIdx.x;
    const int lane = t & 63, wid = t >> 6;
    const int lo   = lane & 15, hi = lane >> 4;
    const int wm   = wid >> 1, wn = wid & 1;

    // staging: rows 128 B (32 fp32); 1 DMA = 8 rows; wave w -> rows [32w,32w+32).
    const int lrow = lane >> 3;                                // 0..7; row&7 == lrow
    const int lchk = ((lane & 7) ^ lrow) << 4;                 // pre-swizzled src chunk
    const char* aSrc = (const char*)(X  + (size_t)(m0 + 32 * wid + lrow) * DD) + lchk;
    const char* bSrc = (const char*)(Wq + (size_t)(n0 + 32 * wid + lrow) * DD) + lchk;

    f32x4 acc[4][4] = {};

    auto stage = [&](float* Ab, float* Bb, int tt) {
#pragma unroll
        for (int i = 0; i < 4; ++i) {
            GLOAD_LDS16(aSrc + (size_t)i * (8 * DD * 4) + (size_t)tt * 128,
                        (char*)Ab + (32 * wid + 8 * i) * 128);
            GLOAD_LDS16(bSrc + (size_t)i * (8 * DD * 4) + (size_t)tt * 128,
                        (char*)Bb + (32 * wid + 8 * i) * 128);
        }
    };
    auto compute = [&](const float* Ab, const float* Bb) {
        bf16x8 a[4], b[4];
#pragma unroll
        for (int mi = 0; mi < 4; ++mi) {
            const int ar = wm * 64 + mi * 16 + lo;
            const int sw = (ar & 7) << 4;
            f32x4 f0 = *reinterpret_cast<const f32x4*>((const char*)Ab + ar * 128 + ((32 * hi) ^ sw));
            f32x4 f1 = *reinterpret_cast<const f32x4*>((const char*)Ab + ar * 128 + ((32 * hi + 16) ^ sw));
            a[mi] = cvt48(f0, f1);
        }
#pragma unroll
        for (int ni = 0; ni < 4; ++ni) {
            const int br = wn * 64 + ni * 16 + lo;
            const int sw = (br & 7) << 4;
            f32x4 f0 = *reinterpret_cast<const f32x4*>((const char*)Bb + br * 128 + ((32 * hi) ^ sw));
            f32x4 f1 = *reinterpret_cast<const f32x4*>((const char*)Bb + br * 128 + ((32 * hi + 16) ^ sw));
            b[ni] = cvt48(f0, f1);
        }
        __builtin_amdgcn_s_setprio(1);
#pragma unroll
        for (int mi = 0; mi < 4; ++mi)
#pragma unroll
            for (int ni = 0; ni < 4; ++ni)
                acc[mi][ni] = MFMA16(a[mi], b[ni], acc[mi][ni]);
        __builtin_amdgcn_s_setprio(0);
    };

    float *Ac = As0, *Bc = Bs0, *An = As1, *Bn = Bs1;
    stage(Ac, Bc, 0);
    stage(An, Bn, 1);
    for (int tt = 0; tt < 15; ++tt) {
        WAITCNT_VM(8);                      // tile tt's 8 DMAs done (8 newer stay in flight)
        __builtin_amdgcn_s_barrier();       // now tile tt visible to ALL waves
        compute(Ac, Bc);
        WAITCNT_LGKM0();                    // my LDS reads done before buffer reuse
        __builtin_amdgcn_s_barrier();       // all waves done reading buffer
        if (tt < 14) stage(Ac, Bc, tt + 2); // refill consumed buffer
        float* tmp;
        tmp = Ac; Ac = An; An = tmp;
        tmp = Bc; Bc = Bn; Bn = tmp;
    }
    WAITCNT_VM(0);
    __builtin_amdgcn_s_barrier();
    compute(Ac, Bc);                        // tile 15

    // Epilogue: C/D col = lane&15 (n), row = 4*hi + r (m)
#pragma unroll
    for (int mi = 0; mi < 4; ++mi) {
#pragma unroll
        for (int ni = 0; ni < 4; ++ni) {
            const int n = n0 + wn * 64 + ni * 16 + lo;
            const float bias = bq[n];
            const int h_ = n >> 6, e_ = n & 63;
#pragma unroll
            for (int r = 0; r < 4; ++r) {
                const int m = m0 + wm * 64 + mi * 16 + hi * 4 + r;
                const float val = acc[mi][ni][r] + bias;
                const int b_ = m >> 11, s_ = m & (SS - 1);
                const size_t bh = (size_t)(b_ * HH + h_);
                if (z == 0)
                    qh[(bh * SS + s_) * DKK + e_] = (__bf16)val;
                else if (z == 1)
                    kh[(bh * SS + s_) * DKK + e_] = (__bf16)val;
                else
                    vt[(bh * DKK + e_) * SS + s_] = (__bf16)val;
            }
        }
    }
}

// ---------------------------------------------------------------------------
// Kernel 2: flash attention — R6 structure (measured 77 us) re-gridded:
// 2 waves/block, 32 q-rows/block, KV tile = 64 -> 2048 blocks (~8/CU by
// grid, 7 by LDS 20.5 KB). Swapped QK^T, per-wave P staging, XOR-swizzled
// K/V LDS (write+read).
// ---------------------------------------------------------------------------
__global__ __launch_bounds__(128) void attn_kernel(
    const __bf16* __restrict__ qh, const __bf16* __restrict__ kh,
    const __bf16* __restrict__ vt, __bf16* __restrict__ concat)
{
    const int q0 = blockIdx.x * 32;
    const int bh = blockIdx.y;                 // b*H + h
    const int b_ = bh >> 3, h_ = bh & 7;
    const size_t base = (size_t)bh * SS * DKK;
    const __bf16* qhp = qh + base;
    const __bf16* khp = kh + base;
    const __bf16* vtp = vt + base;             // [DK][S] per (b,h)

    const int t    = threadIdx.x;
    const int lane = t & 63, wid = t >> 6;     // wid in {0,1}
    const int lo   = lane & 15, hi = lane >> 4;

    __shared__ __align__(16) __bf16 Ks[64 * 64];    // swizzled [kv][d], 8 KB
    __shared__ __align__(16) __bf16 Vts[64 * 64];   // swizzled [e][kv], 8 KB
    __shared__ __align__(16) __bf16 Ps[2][16][72];  // per-wave P [q][kv]

    char* KsB  = (char*)Ks;
    char* VtsB = (char*)Vts;

    // staging: wave w covers rows [32w,32w+32) via 4 issues of 8 rows
    const int sr   = lane >> 3;                  // 0..7; row&7 == sr
    const int gcb  = (lane & 7) << 4;            // linear col byte
    const int scb  = gcb ^ (sr << 4);            // swizzled col byte
    const int srow = 32 * wid + sr;

    bf16x8 qf[2];
#pragma unroll
    for (int kk = 0; kk < 2; ++kk)
        qf[kk] = *reinterpret_cast<const bf16x8*>(
            &qhp[(size_t)(q0 + 16 * wid + lo) * DKK + 32 * kk + 8 * hi]);

    f32x4 acc[4] = {};
    float m_run = -INFINITY, l_run = 0.f;

    for (int kv0 = 0; kv0 < SS; kv0 += 64) {
        bf16x8 kreg[4], vreg[4];
#pragma unroll
        for (int j = 0; j < 4; ++j) {
            kreg[j] = *reinterpret_cast<const bf16x8*>(
                (const char*)&khp[(size_t)(kv0 + srow + 8 * j) * DKK] + gcb);
            vreg[j] = *reinterpret_cast<const bf16x8*>(
                (const char*)&vtp[(size_t)(srow + 8 * j) * SS + kv0] + gcb);
        }

        __syncthreads();
#pragma unroll
        for (int j = 0; j < 4; ++j) {
            *reinterpret_cast<bf16x8*>(KsB  + (srow + 8 * j) * 128 + scb) = kreg[j];
            *reinterpret_cast<bf16x8*>(VtsB + (srow + 8 * j) * 128 + scb) = vreg[j];
        }
        __syncthreads();

        // scores: S^T[kv 64][q 16] via mfma(K, Q)
        f32x4 sc[4] = {};
#pragma unroll
        for (int kk = 0; kk < 2; ++kk) {
            bf16x8 kf[4];
#pragma unroll
            for (int f = 0; f < 4; ++f) {
                const int row = 16 * f + lo;
                const int cb  = (64 * kk + 16 * hi) ^ ((row & 7) << 4);
                kf[f] = *reinterpret_cast<const bf16x8*>(KsB + row * 128 + cb);
            }
#pragma unroll
            for (int f = 0; f < 4; ++f)
                sc[f] = MFMA16(kf[f], qf[kk], sc[f]);
        }

        // online softmax (lane owns q = lo)
        {
            float mx = -1e30f;
#pragma unroll
            for (int f = 0; f < 4; ++f)
#pragma unroll
                for (int r = 0; r < 4; ++r)
                    mx = fmaxf(mx, sc[f][r]);
            mx = fmaxf(mx, __shfl_xor(mx, 16));
            mx = fmaxf(mx, __shfl_xor(mx, 32));
            const float mnew = fmaxf(m_run, mx * 0.125f);
            const float scl  = __expf(m_run - mnew);
            float rs = 0.f;
#pragma unroll
            for (int f = 0; f < 4; ++f) {
                bf16x4 pk;
#pragma unroll
                for (int r = 0; r < 4; ++r) {
                    const float e = __expf(fmaf(sc[f][r], 0.125f, -mnew));
                    rs += e;
                    pk[r] = (__bf16)e;
                }
                *reinterpret_cast<bf16x4*>(&Ps[wid][lo][16 * f + 4 * hi]) = pk;
            }
            rs += __shfl_xor(rs, 16);
            rs += __shfl_xor(rs, 32);
            l_run = l_run * scl + rs;
            m_run = mnew;
#pragma unroll
            for (int f = 0; f < 4; ++f)
                acc[f] *= scl;
        }
        // no block barrier: Ps is per-wave

        // PV: O^T += mfma(V^T, P^T)
#pragma unroll
        for (int kk = 0; kk < 2; ++kk) {
            bf16x8 pb = *reinterpret_cast<const bf16x8*>(&Ps[wid][lo][32 * kk + 8 * hi]);
#pragma unroll
            for (int f = 0; f < 4; ++f) {
                const int row = 16 * f + lo;
                const int cb  = (64 * kk + 16 * hi) ^ ((row & 7) << 4);
                bf16x8 vf = *reinterpret_cast<const bf16x8*>(VtsB + row * 128 + cb);
                acc[f] = MFMA16(vf, pb, acc[f]);
            }
        }
    }

    {
        const float inv = 1.0f / l_run;
        const int qrow = q0 + 16 * wid + lo;
        const size_t ob = ((size_t)b_ * SS + qrow) * HDK + h_ * DKK;
#pragma unroll
        for (int f = 0; f < 4; ++f) {
            bf16x4 o;
#pragma unroll
            for (int r = 0; r < 4; ++r)
                o[r] = (__bf16)(acc[f][r] * inv);
            *reinterpret_cast<bf16x4*>(&concat[ob + 16 * f + 4 * hi]) = o;
        }
    }
}

// ---------------------------------------------------------------------------
// Kernel 3: output projection. Tile 64(M)x128(N), BK=32, depth-2 counted-
// vmcnt pipeline (5 DMAs/wave/tile -> steady 10 in flight, wait vmcnt(5)).
// ---------------------------------------------------------------------------
__global__ __launch_bounds__(256) void outproj_kernel(
    const __bf16* __restrict__ concat, const float* __restrict__ Wout,
    const float* __restrict__ bout, float* __restrict__ out)
{
    const int m0 = blockIdx.x * 64;
    const int n0 = blockIdx.y * 128;

    __shared__ __align__(16) __bf16 As0[64 * 32], As1[64 * 32];     // 4 KB each
    __shared__ __align__(16) float  Bs0[128 * 32], Bs1[128 * 32];   // 16 KB each

    const int t    = threadIdx.x;
    const int lane = t & 63, wid = t >> 6;
    const int lo   = lane & 15, hi = lane >> 4;
    const int wm   = wid >> 1, wn = wid & 1;

    // A: rows 64 B (32 bf16); 1 DMA = 16 rows; wave w -> rows [16w,16w+16).
    const int ar4  = lane >> 2;                                   // 0..15; row&3 == ar4&3
    const int achk = ((lane & 3) ^ (ar4 & 3)) << 4;
    const char* aSrc = (const char*)(concat + (size_t)(m0 + 16 * wid + ar4) * HDK) + achk;
    // B: rows 128 B (32 fp32); 4 DMAs/wave; wave w -> rows [32w,32w+32).
    const int br8  = lane >> 3;                                   // 0..7
    const int bchk = ((lane & 7) ^ br8) << 4;
    const char* bSrc = (const char*)(Wout + (size_t)(n0 + 32 * wid + br8) * HDK) + bchk;

    f32x4 acc[2][4] = {};

    auto stage = [&](__bf16* Ab, float* Bb, int tt) {
        GLOAD_LDS16(aSrc + (size_t)tt * 64, (char*)Ab + (16 * wid) * 64);
#pragma unroll
        for (int i = 0; i < 4; ++i)
            GLOAD_LDS16(bSrc + (size_t)i * (8 * HDK * 4) + (size_t)tt * 128,
                        (char*)Bb + (32 * wid + 8 * i) * 128);
    };
    auto compute = [&](const __bf16* Ab, const float* Bb) {
        bf16x8 a[2], b[4];
#pragma unroll
        for (int mi = 0; mi < 2; ++mi) {
            const int ar = wm * 32 + mi * 16 + lo;
            a[mi] = *reinterpret_cast<const bf16x8*>(
                (const char*)Ab + ar * 64 + ((16 * hi) ^ ((ar & 3) << 4)));
        }
#pragma unroll
        for (int ni = 0; ni < 4; ++ni) {
            const int br = wn * 64 + ni * 16 + lo;
            const int sw = (br & 7) << 4;
            f32x4 f0 = *reinterpret_cast<const f32x4*>((const char*)Bb + br * 128 + ((32 * hi) ^ sw));
            f32x4 f1 = *reinterpret_cast<const f32x4*>((const char*)Bb + br * 128 + ((32 * hi + 16) ^ sw));
            b[ni] = cvt48(f0, f1);
        }
        __builtin_amdgcn_s_setprio(1);
#pragma unroll
        for (int mi = 0; mi < 2; ++mi)
#pragma unroll
            for (int ni = 0; ni < 4; ++ni)
                acc[mi][ni] = MFMA16(a[mi], b[ni], acc[mi][ni]);
        __builtin_amdgcn_s_setprio(0);
    };

    __bf16 *Ac = As0, *An = As1;
    float  *Bc = Bs0, *Bn = Bs1;
    stage(Ac, Bc, 0);
    stage(An, Bn, 1);
    for (int tt = 0; tt < 15; ++tt) {
        WAITCNT_VM(5);
        __builtin_amdgcn_s_barrier();
        compute(Ac, Bc);
        WAITCNT_LGKM0();
        __builtin_amdgcn_s_barrier();
        if (tt < 14) stage(Ac, Bc, tt + 2);
        __bf16* ta = Ac; Ac = An; An = ta;
        float*  tb = Bc; Bc = Bn; Bn = tb;
    }
    WAITCNT_VM(0);
    __builtin_amdgcn_s_barrier();
    compute(Ac, Bc);

#pragma unroll
    for (int mi = 0; mi < 2; ++mi) {
#pragma unroll
        for (int ni = 0; ni < 4; ++ni) {
            const int n = n0 + wn * 64 + ni * 16 + lo;
            const float bias = bout[n];
#pragma unroll
            for (int r = 0; r < 4; ++r) {
                const int m = m0 + wm * 32 + mi * 16 + hi * 4 + r;
                out[(size_t)m * DD + n] = acc[mi][ni][r] + bias;
            }
        }
    }
}

// ---------------------------------------------------------------------------
extern "C" void kernel_launch(void* const* d_in, const int* in_sizes, int n_in,
                              void* d_out, int out_size, void* d_ws, size_t ws_size,
                              hipStream_t stream)
{
    (void)in_sizes; (void)n_in; (void)out_size; (void)ws_size;
    const float* q    = (const float*)d_in[0];
    const float* k    = (const float*)d_in[1];
    const float* v    = (const float*)d_in[2];
    const float* Wq   = (const float*)d_in[3];
    const float* bq   = (const float*)d_in[4];
    const float* Wout = (const float*)d_in[5];
    const float* bout = (const float*)d_in[6];
    float* out = (float*)d_out;

    char* ws = (char*)d_ws;
    __bf16* qh = (__bf16*)(ws);                      // 8 MiB  [B,H,S,DK]
    __bf16* kh = (__bf16*)(ws + (8u << 20));         // 8 MiB  [B,H,S,DK]
    __bf16* vt = (__bf16*)(ws + (16u << 20));        // 8 MiB  [B,H,DK,S]
    __bf16* cc = (__bf16*)(ws + (24u << 20));        // 8 MiB  [B,S,H*DK]

    proj_kernel<<<dim3(BB * SS / 128, HDK / 128, 3), 256, 0, stream>>>(q, k, v, Wq, bq, qh, kh, vt);
    attn_kernel<<<dim3(SS / 32, BB * HH), 128, 0, stream>>>(qh, kh, vt, cc);
    outproj_kernel<<<dim3(BB * SS / 64, DD / 128), 256, 0, stream>>>(cc, Wout, bout, out);
}

// Round 9
// 213.140 us; speedup vs baseline: 1.1926x; 1.1926x over previous
//
#include <hip/hip_runtime.h>

// Problem constants
#define BB 4
#define SS 2048
#define DD 512
#define HH 8
#define DKK 64
#define HDK 512   // H*DK

typedef __attribute__((ext_vector_type(4))) float f32x4;
typedef __attribute__((ext_vector_type(8))) __bf16 bf16x8;
typedef __attribute__((ext_vector_type(4))) __bf16 bf16x4;

#define MFMA16(a, b, c) __builtin_amdgcn_mfma_f32_16x16x32_bf16((a), (b), (c), 0, 0, 0)

#define GLOAD_LDS16(gptr, lptr)                                                    \
    __builtin_amdgcn_global_load_lds(                                              \
        (const __attribute__((address_space(1))) void*)(gptr),                     \
        (__attribute__((address_space(3))) void*)(lptr), 16, 0, 0)

__device__ inline bf16x8 cvt48(const f32x4 f0, const f32x4 f1) {
    bf16x8 w;
    w[0] = (__bf16)f0[0]; w[1] = (__bf16)f0[1]; w[2] = (__bf16)f0[2]; w[3] = (__bf16)f0[3];
    w[4] = (__bf16)f1[0]; w[5] = (__bf16)f1[1]; w[6] = (__bf16)f1[2]; w[7] = (__bf16)f1[3];
    return w;
}

// ---------------------------------------------------------------------------
// Kernel 0: convert Wq and Wout (fp32 -> bf16), layout unchanged.
// 512*512 elts each; 65536 threads x 8 elts.
// ---------------------------------------------------------------------------
__global__ __launch_bounds__(256) void wconv_kernel(
    const float* __restrict__ Wq, const float* __restrict__ Wout,
    __bf16* __restrict__ Wqb, __bf16* __restrict__ Wob)
{
    const int tid = blockIdx.x * 256 + threadIdx.x;
    const float* src;
    __bf16* dst;
    int off;
    if (tid < 32768) { src = Wq;   dst = Wqb; off = tid * 8; }
    else             { src = Wout; dst = Wob; off = (tid - 32768) * 8; }
    f32x4 f0 = *reinterpret_cast<const f32x4*>(src + off);
    f32x4 f1 = *reinterpret_cast<const f32x4*>(src + off + 4);
    *reinterpret_cast<bf16x8*>(dst + off) = cvt48(f0, f1);
}

// ---------------------------------------------------------------------------
// Kernel 1: projection GEMM, 128x128 tile, BK=32, 2-phase dbuf gload_lds.
// A = X fp32 in LDS (cvt at frag read), B = Wqb bf16 in LDS.
// LDS 48 KB -> 3 blocks/CU; grid 768 = ONE round (the R8 variants ran 2
// rounds at 2/CU — that was the invariant limiter).
// Grid (n=4, m=64, z=3): same-A blocks adjacent for L2 reuse.
//   z=0 -> qh [B,H,S,DK], z=1 -> kh [B,H,S,DK], z=2 -> vt [B,H,DK,S]
// ---------------------------------------------------------------------------
__global__ __launch_bounds__(256) void proj_kernel(
    const float* __restrict__ q, const float* __restrict__ k, const float* __restrict__ v,
    const __bf16* __restrict__ Wqb, const float* __restrict__ bq,
    __bf16* __restrict__ qh, __bf16* __restrict__ kh, __bf16* __restrict__ vt)
{
    const int z  = blockIdx.z;
    const float* X = (z == 0) ? q : (z == 1) ? k : v;
    const int n0 = blockIdx.x * 128;
    const int m0 = blockIdx.y * 128;

    __shared__ __align__(16) float  As[2][128 * 32];   // 16 KB per buf
    __shared__ __align__(16) __bf16 Bs[2][128 * 32];   //  8 KB per buf

    const int t    = threadIdx.x;
    const int lane = t & 63, wid = t >> 6;
    const int lo   = lane & 15, hi = lane >> 4;
    const int wm   = wid >> 1, wn = wid & 1;

    // A staging: fp32 rows 128 B (8 chunks of 16 B). 1 DMA = 8 rows; 4/wave.
    // lane -> row r0+(lane>>3), LDS chunk lane&7, src chunk (lane&7)^(row&7).
    const int alr  = lane >> 3;                               // row&7 == alr
    const int achk = ((lane & 7) ^ alr) << 4;
    const char* aSrc = (const char*)(X + (size_t)(m0 + 32 * wid + alr) * DD) + achk;
    // B staging: bf16 rows 64 B (4 chunks). 1 DMA = 16 rows; 2/wave.
    // lane -> row r0+(lane>>2), LDS chunk lane&3, src chunk (lane&3)^((row>>1)&3).
    const int blr  = lane >> 2;
    const int bchk = ((lane & 3) ^ ((lane >> 3) & 3)) << 4;
    const char* bSrc = (const char*)(Wqb + (size_t)(n0 + 32 * wid + blr) * DD) + bchk;

    f32x4 acc[4][4] = {};

    auto stage = [&](int buf, int tt) {
#pragma unroll
        for (int i = 0; i < 4; ++i)
            GLOAD_LDS16(aSrc + (size_t)i * (8 * DD * 4) + (size_t)tt * 128,
                        (char*)As[buf] + (32 * wid + 8 * i) * 128);
#pragma unroll
        for (int i = 0; i < 2; ++i)
            GLOAD_LDS16(bSrc + (size_t)i * (16 * DD * 2) + (size_t)tt * 64,
                        (char*)Bs[buf] + (32 * wid + 16 * i) * 64);
    };
    auto compute = [&](int buf) {
        bf16x8 a[4], b[4];
#pragma unroll
        for (int mi = 0; mi < 4; ++mi) {
            const int ar = wm * 64 + mi * 16 + lo;
            const int sw = (ar & 7);
            f32x4 f0 = *reinterpret_cast<const f32x4*>(
                (const char*)As[buf] + ar * 128 + (((2 * hi) ^ sw) << 4));
            f32x4 f1 = *reinterpret_cast<const f32x4*>(
                (const char*)As[buf] + ar * 128 + (((2 * hi + 1) ^ sw) << 4));
            a[mi] = cvt48(f0, f1);
        }
#pragma unroll
        for (int ni = 0; ni < 4; ++ni) {
            const int br = wn * 64 + ni * 16 + lo;
            const int cb = (hi ^ ((lo >> 1) & 3)) << 4;
            b[ni] = *reinterpret_cast<const bf16x8*>((const char*)Bs[buf] + br * 64 + cb);
        }
        __builtin_amdgcn_s_setprio(1);
#pragma unroll
        for (int mi = 0; mi < 4; ++mi)
#pragma unroll
            for (int ni = 0; ni < 4; ++ni)
                acc[mi][ni] = MFMA16(a[mi], b[ni], acc[mi][ni]);
        __builtin_amdgcn_s_setprio(0);
    };

    stage(0, 0);
    __syncthreads();
    int cur = 0;
    for (int tt = 0; tt < 16; ++tt) {
        if (tt < 15) stage(cur ^ 1, tt + 1);   // issue BEFORE compute
        compute(cur);
        __syncthreads();                        // drains DMAs (hidden under compute)
        cur ^= 1;
    }

    // Epilogue: C/D col = lane&15 (n), row = 4*hi + r (m)
#pragma unroll
    for (int mi = 0; mi < 4; ++mi) {
#pragma unroll
        for (int ni = 0; ni < 4; ++ni) {
            const int n = n0 + wn * 64 + ni * 16 + lo;
            const float bias = bq[n];
            const int h_ = n >> 6, e_ = n & 63;
#pragma unroll
            for (int r = 0; r < 4; ++r) {
                const int m = m0 + wm * 64 + mi * 16 + hi * 4 + r;
                const float val = acc[mi][ni][r] + bias;
                const int b_ = m >> 11, s_ = m & (SS - 1);
                const size_t bh = (size_t)(b_ * HH + h_);
                if (z == 0)
                    qh[(bh * SS + s_) * DKK + e_] = (__bf16)val;
                else if (z == 1)
                    kh[(bh * SS + s_) * DKK + e_] = (__bf16)val;
                else
                    vt[(bh * DKK + e_) * SS + s_] = (__bf16)val;
            }
        }
    }
}

// ---------------------------------------------------------------------------
// Kernel 2: flash attention — R5-measured 77 us version, verbatim.
// 4 waves, 16 q-rows/wave, 64 q-rows/block, KV tile 64, swapped QK^T,
// per-wave P staging, XOR-swizzled K/V LDS.
// ---------------------------------------------------------------------------
__global__ __launch_bounds__(256) void attn_kernel(
    const __bf16* __restrict__ qh, const __bf16* __restrict__ kh,
    const __bf16* __restrict__ vt, __bf16* __restrict__ concat)
{
    const int q0 = blockIdx.x * 64;
    const int bh = blockIdx.y;                 // b*H + h
    const int b_ = bh >> 3, h_ = bh & 7;
    const size_t base = (size_t)bh * SS * DKK;
    const __bf16* qhp = qh + base;
    const __bf16* khp = kh + base;
    const __bf16* vtp = vt + base;             // [DK][S] per (b,h)

    const int t    = threadIdx.x;
    const int lane = t & 63, wid = t >> 6;
    const int lo   = lane & 15, hi = lane >> 4;

    __shared__ __align__(16) __bf16 Ks[64 * 64];    // swizzled [kv][d]
    __shared__ __align__(16) __bf16 Vts[64 * 64];   // swizzled [e][kv]
    __shared__ __align__(16) __bf16 Ps[4][16][72];  // per-wave P [q][kv]

    char* KsB  = (char*)Ks;
    char* VtsB = (char*)Vts;

    const int sr   = lane >> 3;                  // 0..7
    const int gcb  = (lane & 7) << 4;            // linear col byte
    const int scb  = gcb ^ (sr << 4);            // swizzled col byte
    const int srow = 16 * wid + sr;

    bf16x8 qf[2];
#pragma unroll
    for (int kk = 0; kk < 2; ++kk)
        qf[kk] = *reinterpret_cast<const bf16x8*>(
            &qhp[(size_t)(q0 + 16 * wid + lo) * DKK + 32 * kk + 8 * hi]);

    f32x4 acc[4] = {};
    float m_run = -INFINITY, l_run = 0.f;

    for (int kv0 = 0; kv0 < SS; kv0 += 64) {
        bf16x8 kr0 = *reinterpret_cast<const bf16x8*>(
            (const char*)&khp[(size_t)(kv0 + srow) * DKK] + gcb);
        bf16x8 kr1 = *reinterpret_cast<const bf16x8*>(
            (const char*)&khp[(size_t)(kv0 + srow + 8) * DKK] + gcb);
        bf16x8 vr0 = *reinterpret_cast<const bf16x8*>(
            (const char*)&vtp[(size_t)srow * SS + kv0] + gcb);
        bf16x8 vr1 = *reinterpret_cast<const bf16x8*>(
            (const char*)&vtp[(size_t)(srow + 8) * SS + kv0] + gcb);

        __syncthreads();
        *reinterpret_cast<bf16x8*>(KsB  + srow * 128 + scb)       = kr0;
        *reinterpret_cast<bf16x8*>(KsB  + (srow + 8) * 128 + scb) = kr1;
        *reinterpret_cast<bf16x8*>(VtsB + srow * 128 + scb)       = vr0;
        *reinterpret_cast<bf16x8*>(VtsB + (srow + 8) * 128 + scb) = vr1;
        __syncthreads();

        // scores: S^T[kv 64][q 16] via mfma(K, Q)
        f32x4 sc[4] = {};
#pragma unroll
        for (int kk = 0; kk < 2; ++kk) {
            bf16x8 kf[4];
#pragma unroll
            for (int f = 0; f < 4; ++f) {
                const int row = 16 * f + lo;
                const int cb  = (64 * kk + 16 * hi) ^ ((row & 7) << 4);
                kf[f] = *reinterpret_cast<const bf16x8*>(KsB + row * 128 + cb);
            }
#pragma unroll
            for (int f = 0; f < 4; ++f)
                sc[f] = MFMA16(kf[f], qf[kk], sc[f]);
        }

        // online softmax (lane owns q = lo)
        {
            float mx = -1e30f;
#pragma unroll
            for (int f = 0; f < 4; ++f)
#pragma unroll
                for (int r = 0; r < 4; ++r)
                    mx = fmaxf(mx, sc[f][r]);
            mx = fmaxf(mx, __shfl_xor(mx, 16));
            mx = fmaxf(mx, __shfl_xor(mx, 32));
            const float mnew = fmaxf(m_run, mx * 0.125f);
            const float scl  = __expf(m_run - mnew);
            float rs = 0.f;
#pragma unroll
            for (int f = 0; f < 4; ++f) {
                bf16x4 pk;
#pragma unroll
                for (int r = 0; r < 4; ++r) {
                    const float e = __expf(fmaf(sc[f][r], 0.125f, -mnew));
                    rs += e;
                    pk[r] = (__bf16)e;
                }
                *reinterpret_cast<bf16x4*>(&Ps[wid][lo][16 * f + 4 * hi]) = pk;
            }
            rs += __shfl_xor(rs, 16);
            rs += __shfl_xor(rs, 32);
            l_run = l_run * scl + rs;
            m_run = mnew;
#pragma unroll
            for (int f = 0; f < 4; ++f)
                acc[f] *= scl;
        }
        // no block barrier: Ps is per-wave

        // PV: O^T += mfma(V^T, P^T)
#pragma unroll
        for (int kk = 0; kk < 2; ++kk) {
            bf16x8 pb = *reinterpret_cast<const bf16x8*>(&Ps[wid][lo][32 * kk + 8 * hi]);
#pragma unroll
            for (int f = 0; f < 4; ++f) {
                const int row = 16 * f + lo;
                const int cb  = (64 * kk + 16 * hi) ^ ((row & 7) << 4);
                bf16x8 vf = *reinterpret_cast<const bf16x8*>(VtsB + row * 128 + cb);
                acc[f] = MFMA16(vf, pb, acc[f]);
            }
        }
    }

    {
        const float inv = 1.0f / l_run;
        const int qrow = q0 + 16 * wid + lo;
        const size_t ob = ((size_t)b_ * SS + qrow) * HDK + h_ * DKK;
#pragma unroll
        for (int f = 0; f < 4; ++f) {
            bf16x4 o;
#pragma unroll
            for (int r = 0; r < 4; ++r)
                o[r] = (__bf16)(acc[f][r] * inv);
            *reinterpret_cast<bf16x4*>(&concat[ob + 16 * f + 4 * hi]) = o;
        }
    }
}

// ---------------------------------------------------------------------------
// Kernel 3: output projection, 128x128 tile, BK=32, all-bf16 LDS (32 KB
// dbuf -> 4 blocks/CU; 256 blocks = one round). A = cc, B = Wob.
// ---------------------------------------------------------------------------
__global__ __launch_bounds__(256) void outproj_kernel(
    const __bf16* __restrict__ concat, const __bf16* __restrict__ Wob,
    const float* __restrict__ bout, float* __restrict__ out)
{
    const int n0 = blockIdx.x * 128;
    const int m0 = blockIdx.y * 128;

    __shared__ __align__(16) __bf16 As[2][128 * 32];   // 8 KB per buf
    __shared__ __align__(16) __bf16 Bs[2][128 * 32];

    const int t    = threadIdx.x;
    const int lane = t & 63, wid = t >> 6;
    const int lo   = lane & 15, hi = lane >> 4;
    const int wm   = wid >> 1, wn = wid & 1;

    // bf16 rows 64 B, 1 DMA = 16 rows; 2 DMAs/wave per matrix.
    const int blr  = lane >> 2;
    const int bchk = ((lane & 3) ^ ((lane >> 3) & 3)) << 4;
    const char* aSrc = (const char*)(concat + (size_t)(m0 + 32 * wid + blr) * HDK) + bchk;
    const char* bSrc = (const char*)(Wob    + (size_t)(n0 + 32 * wid + blr) * HDK) + bchk;

    f32x4 acc[4][4] = {};

    auto stage = [&](int buf, int tt) {
#pragma unroll
        for (int i = 0; i < 2; ++i) {
            GLOAD_LDS16(aSrc + (size_t)i * (16 * HDK * 2) + (size_t)tt * 64,
                        (char*)As[buf] + (32 * wid + 16 * i) * 64);
            GLOAD_LDS16(bSrc + (size_t)i * (16 * HDK * 2) + (size_t)tt * 64,
                        (char*)Bs[buf] + (32 * wid + 16 * i) * 64);
        }
    };
    auto compute = [&](int buf) {
        bf16x8 a[4], b[4];
        const int cb = (hi ^ ((lo >> 1) & 3)) << 4;
#pragma unroll
        for (int mi = 0; mi < 4; ++mi) {
            const int ar = wm * 64 + mi * 16 + lo;
            a[mi] = *reinterpret_cast<const bf16x8*>((const char*)As[buf] + ar * 64 + cb);
        }
#pragma unroll
        for (int ni = 0; ni < 4; ++ni) {
            const int br = wn * 64 + ni * 16 + lo;
            b[ni] = *reinterpret_cast<const bf16x8*>((const char*)Bs[buf] + br * 64 + cb);
        }
        __builtin_amdgcn_s_setprio(1);
#pragma unroll
        for (int mi = 0; mi < 4; ++mi)
#pragma unroll
            for (int ni = 0; ni < 4; ++ni)
                acc[mi][ni] = MFMA16(a[mi], b[ni], acc[mi][ni]);
        __builtin_amdgcn_s_setprio(0);
    };

    stage(0, 0);
    __syncthreads();
    int cur = 0;
    for (int tt = 0; tt < 16; ++tt) {
        if (tt < 15) stage(cur ^ 1, tt + 1);
        compute(cur);
        __syncthreads();
        cur ^= 1;
    }

#pragma unroll
    for (int mi = 0; mi < 4; ++mi) {
#pragma unroll
        for (int ni = 0; ni < 4; ++ni) {
            const int n = n0 + wn * 64 + ni * 16 + lo;
            const float bias = bout[n];
#pragma unroll
            for (int r = 0; r < 4; ++r) {
                const int m = m0 + wm * 64 + mi * 16 + hi * 4 + r;
                out[(size_t)m * DD + n] = acc[mi][ni][r] + bias;
            }
        }
    }
}

// ---------------------------------------------------------------------------
extern "C" void kernel_launch(void* const* d_in, const int* in_sizes, int n_in,
                              void* d_out, int out_size, void* d_ws, size_t ws_size,
                              hipStream_t stream)
{
    (void)in_sizes; (void)n_in; (void)out_size; (void)ws_size;
    const float* q    = (const float*)d_in[0];
    const float* k    = (const float*)d_in[1];
    const float* v    = (const float*)d_in[2];
    const float* Wq   = (const float*)d_in[3];
    const float* bq   = (const float*)d_in[4];
    const float* Wout = (const float*)d_in[5];
    const float* bout = (const float*)d_in[6];
    float* out = (float*)d_out;

    char* ws = (char*)d_ws;
    __bf16* qh  = (__bf16*)(ws);                          // 8 MiB [B,H,S,DK]
    __bf16* kh  = (__bf16*)(ws + (8u << 20));             // 8 MiB [B,H,S,DK]
    __bf16* vt  = (__bf16*)(ws + (16u << 20));            // 8 MiB [B,H,DK,S]
    __bf16* cc  = (__bf16*)(ws + (24u << 20));            // 8 MiB [B,S,H*DK]
    __bf16* Wqb = (__bf16*)(ws + (32u << 20));            // 0.5 MiB
    __bf16* Wob = (__bf16*)(ws + (32u << 20) + (512u << 10)); // 0.5 MiB

    wconv_kernel<<<256, 256, 0, stream>>>(Wq, Wout, Wqb, Wob);
    proj_kernel<<<dim3(HDK / 128, BB * SS / 128, 3), 256, 0, stream>>>(q, k, v, Wqb, bq, qh, kh, vt);
    attn_kernel<<<dim3(SS / 64, BB * HH), 256, 0, stream>>>(qh, kh, vt, cc);
    outproj_kernel<<<dim3(DD / 128, BB * SS / 128), 256, 0, stream>>>(cc, Wob, bout, out);
}